// Round 1
// baseline (1956.595 us; speedup 1.0000x reference)
//
#include <hip/hip_runtime.h>
#include <math.h>

#define NPERSEG 128
#define HOP     64
#define NFRAMES 33
#define NFREQ   65
#define BATCH   2048
#define LEN     2048
#define NSENS   8
#define FEAT    (NFREQ * NFRAMES)   // 2145
#define H1      1024
#define H2      512
#define H3      256
#define NOUT    10

// ---------------------------------------------------------------------------
// Kernel 0: softmax over the 8 sensor weights (trivial).
// ---------------------------------------------------------------------------
__global__ void sf_softmax8(const float* __restrict__ w, float* __restrict__ out) {
    if (threadIdx.x == 0) {
        float m = w[0];
        for (int s = 1; s < NSENS; ++s) m = fmaxf(m, w[s]);
        float e[NSENS];
        float sum = 0.f;
        for (int s = 0; s < NSENS; ++s) { e[s] = expf(w[s] - m); sum += e[s]; }
        float inv = 1.0f / sum;
        for (int s = 0; s < NSENS; ++s) out[s] = e[s] * inv;
    }
}

// ---------------------------------------------------------------------------
// Kernel 1: STFT magnitude + sensor fusion.
// One block per (frame t, batch b). LDS: windowed samples xs[i][s], trig
// tables, fused[65] accumulator. 520 (f,s) pairs over 256 threads; each does
// a 128-tap rDFT (incremental trig index, magnitude is sign-insensitive so we
// accumulate +sin). Output h0[b][f*33 + t] = sum_s w_s * |spec|/64.
// ---------------------------------------------------------------------------
__global__ __launch_bounds__(256)
void sf_stft_fuse(const float* __restrict__ x,
                  const float* __restrict__ wsoft,
                  float* __restrict__ h0) {
    __shared__ float xs[NPERSEG * NSENS];   // [i][s], window applied
    __shared__ float ct[NPERSEG];
    __shared__ float st[NPERSEG];
    __shared__ float fuse[NFREQ];
    __shared__ float wsens[NSENS];

    const int t   = blockIdx.x;
    const int b   = blockIdx.y;
    const int tid = threadIdx.x;
    const float TWO_PI = 6.28318530717958647692f;

    if (tid < NPERSEG) {
        float ang = TWO_PI * (float)tid / (float)NPERSEG;
        ct[tid] = cosf(ang);
        st[tid] = sinf(ang);
    }
    if (tid < NFREQ) fuse[tid] = 0.f;
    if (tid < NSENS) wsens[tid] = wsoft[tid];

    // Load 128 samples x 8 sensors (zero-padded at sequence edges), windowed.
    const int j0 = t * HOP - NPERSEG / 2;   // original-sequence index of frame sample 0
    for (int e = tid; e < NPERSEG * NSENS; e += 256) {
        int i = e >> 3;          // sample index within frame
        int l = j0 + i;          // index into x's length dim
        float v = 0.f;
        if (l >= 0 && l < LEN) v = x[((long)b * LEN + l) * NSENS + (e & 7)];
        float win = 0.5f - 0.5f * cosf(TWO_PI * (float)i / (float)NPERSEG);
        xs[e] = v * win;
    }
    __syncthreads();

    for (int p = tid; p < NFREQ * NSENS; p += 256) {
        const int f = p >> 3;
        const int s = p & 7;
        float re = 0.f, im = 0.f;
        int k = 0;
        #pragma unroll 16
        for (int i = 0; i < NPERSEG; ++i) {
            float a = xs[(i << 3) + s];
            re = fmaf(a, ct[k], re);
            im = fmaf(a, st[k], im);   // sign of im irrelevant for magnitude
            k = (k + f) & (NPERSEG - 1);
        }
        float mag = sqrtf(re * re + im * im) * (1.0f / 64.0f);  // sum(hann_128) = 64
        atomicAdd(&fuse[f], wsens[s] * mag);
    }
    __syncthreads();

    for (int f = tid; f < NFREQ; f += 256)
        h0[(long)b * FEAT + f * NFRAMES + t] = fuse[f];
}

// ---------------------------------------------------------------------------
// Kernel 2: generic fp32 NT-GEMM with fused bias (+ optional ReLU).
// C[m,n] = act(sum_k A[m,k] * W[n,k] + bias[n]); A: MxK, W: NxK, row-major.
// 64x64 tile, BK=16, 256 threads, 4x4 microtile, float4 LDS reads.
// M is always a multiple of 64 here; N and K are guarded.
// ---------------------------------------------------------------------------
template <int RELU>
__global__ __launch_bounds__(256)
void sf_gemm_nt(const float* __restrict__ A, const float* __restrict__ W,
                const float* __restrict__ bias, float* __restrict__ C,
                int M, int N, int K) {
    const int BM = 64, BK = 16, STR = 68;   // STR keeps float4 alignment, low conflicts
    __shared__ __align__(16) float As[BK * STR];
    __shared__ __align__(16) float Ws[BK * STR];

    const int tid = threadIdx.x;
    const int tx  = tid & 15;   // n-direction
    const int ty  = tid >> 4;   // m-direction
    const int m0  = blockIdx.y * BM;
    const int n0  = blockIdx.x * BM;

    float acc[4][4] = {};

    for (int k0 = 0; k0 < K; k0 += BK) {
        for (int e = tid; e < BM * BK; e += 256) {
            int r = e >> 4;       // row within tile (m or n)
            int k = e & 15;
            bool kok = (k0 + k) < K;
            float va = kok ? A[(long)(m0 + r) * K + k0 + k] : 0.f;
            As[k * STR + r] = va;
            float vw = (kok && (n0 + r) < N) ? W[(long)(n0 + r) * K + k0 + k] : 0.f;
            Ws[k * STR + r] = vw;
        }
        __syncthreads();
        #pragma unroll
        for (int kk = 0; kk < BK; ++kk) {
            const float4 a4 = *(const float4*)&As[kk * STR + ty * 4];
            const float4 w4 = *(const float4*)&Ws[kk * STR + tx * 4];
            const float a[4] = {a4.x, a4.y, a4.z, a4.w};
            const float w[4] = {w4.x, w4.y, w4.z, w4.w};
            #pragma unroll
            for (int i = 0; i < 4; ++i)
                #pragma unroll
                for (int j = 0; j < 4; ++j)
                    acc[i][j] = fmaf(a[i], w[j], acc[i][j]);
        }
        __syncthreads();
    }

    #pragma unroll
    for (int i = 0; i < 4; ++i) {
        int m = m0 + ty * 4 + i;
        #pragma unroll
        for (int j = 0; j < 4; ++j) {
            int n = n0 + tx * 4 + j;
            if (n < N) {
                float v = acc[i][j] + bias[n];
                if (RELU) v = fmaxf(v, 0.f);
                C[(long)m * N + n] = v;
            }
        }
    }
}

// ---------------------------------------------------------------------------
extern "C" void kernel_launch(void* const* d_in, const int* in_sizes, int n_in,
                              void* d_out, int out_size, void* d_ws, size_t ws_size,
                              hipStream_t stream) {
    const float* x  = (const float*)d_in[0];
    const float* sw = (const float*)d_in[1];
    const float* W1 = (const float*)d_in[2];
    const float* b1 = (const float*)d_in[3];
    const float* W2 = (const float*)d_in[4];
    const float* b2 = (const float*)d_in[5];
    const float* W3 = (const float*)d_in[6];
    const float* b3 = (const float*)d_in[7];
    const float* W4 = (const float*)d_in[8];
    const float* b4 = (const float*)d_in[9];
    float* out = (float*)d_out;

    float* ws    = (float*)d_ws;
    float* wsoft = ws;                               // 8 floats (pad to 16)
    float* h0    = ws + 16;                          // 2048 x 2145
    float* h1    = h0 + (size_t)BATCH * FEAT;        // 2048 x 1024
    float* h2    = h1 + (size_t)BATCH * H1;          // 2048 x 512
    float* h3    = h2 + (size_t)BATCH * H2;          // 2048 x 256

    sf_softmax8<<<1, 64, 0, stream>>>(sw, wsoft);
    sf_stft_fuse<<<dim3(NFRAMES, BATCH), 256, 0, stream>>>(x, wsoft, h0);

    sf_gemm_nt<1><<<dim3(H1 / 64,  BATCH / 64), 256, 0, stream>>>(h0, W1, b1, h1, BATCH, H1, FEAT);
    sf_gemm_nt<1><<<dim3(H2 / 64,  BATCH / 64), 256, 0, stream>>>(h1, W2, b2, h2, BATCH, H2, H1);
    sf_gemm_nt<1><<<dim3(H3 / 64,  BATCH / 64), 256, 0, stream>>>(h2, W3, b3, h3, BATCH, H3, H2);
    sf_gemm_nt<0><<<dim3(1,        BATCH / 64), 256, 0, stream>>>(h3, W4, b4, out, BATCH, NOUT, H3);
}

// Round 2
// 1007.148 us; speedup vs baseline: 1.9427x; 1.9427x over previous
//
#include <hip/hip_runtime.h>
#include <hip/hip_bf16.h>
#include <math.h>

#define NPERSEG 128
#define HOP     64
#define NFRAMES 33
#define NFREQ   65
#define BATCH   2048
#define LEN     2048
#define NSENS   8
#define FEAT    (NFREQ * NFRAMES)   // 2145
#define H1      1024
#define H2      512
#define H3      256
#define NOUT    10

// STFT-as-GEMM geometry
#define XROW    2248                // LDS row stride (elems) per sensor: 2248*2/4=1124 words, %32=4 -> conflict-free frags
#define CWROW   136                 // basis row stride: 272B -> 68 words... *2/4: 68? (136*2/4=68, %32=4) conflict-free
#define NB      160                 // basis rows: re at n=f (0..64), im at n=80+f (80..144), rest zero
#define NTILES  10                  // 160/16
#define MT_PER_WAVE 3               // 8 waves * 3 = 24 M-tiles (264 valid rows, rest discarded)

typedef __attribute__((ext_vector_type(8))) short short8;     // 8 bf16 = 4 VGPRs
typedef __attribute__((ext_vector_type(4))) float float4v;    // MFMA C/D

__device__ __forceinline__ unsigned short f2b(float v) {
    __hip_bfloat16 h = __float2bfloat16(v);
    return *reinterpret_cast<unsigned short*>(&h);
}

// ---------------------------------------------------------------------------
// Kernel 0: softmax over the 8 sensor weights.
// ---------------------------------------------------------------------------
__global__ void sf_softmax8(const float* __restrict__ w, float* __restrict__ out) {
    if (threadIdx.x == 0) {
        float m = w[0];
        for (int s = 1; s < NSENS; ++s) m = fmaxf(m, w[s]);
        float e[NSENS];
        float sum = 0.f;
        for (int s = 0; s < NSENS; ++s) { e[s] = expf(w[s] - m); sum += e[s]; }
        float inv = 1.0f / sum;
        for (int s = 0; s < NSENS; ++s) out[s] = e[s] * inv;
    }
}

// ---------------------------------------------------------------------------
// Kernel 0b: windowed DFT basis in bf16, window and 1/64 norm folded in.
// cwg[n][k]: n<65: win[k]*cos(2pi n k/128)/64 ; 80<=n<145: win[k]*sin(...)/64
// (sign of sin irrelevant for magnitude). k in [128,136) and other n: 0.
// Angle reduced exactly via (n*k) mod 128.
// ---------------------------------------------------------------------------
__global__ void sf_basis(unsigned short* __restrict__ cwg) {
    int e = blockIdx.x * 256 + threadIdx.x;
    if (e >= NB * CWROW) return;
    int n = e / CWROW, k = e - n * CWROW;
    const float TWO_PI = 6.28318530717958647692f;
    float v = 0.f;
    if (k < NPERSEG) {
        float win = 0.5f - 0.5f * cosf(TWO_PI * (float)k / (float)NPERSEG);
        if (n < NFREQ) {
            int r = (n * k) & (NPERSEG - 1);
            v = win * cosf(TWO_PI * (float)r / (float)NPERSEG) * (1.0f / 64.0f);
        } else if (n >= 80 && n < 80 + NFREQ) {
            int r = ((n - 80) * k) & (NPERSEG - 1);
            v = win * sinf(TWO_PI * (float)r / (float)NPERSEG) * (1.0f / 64.0f);
        }
    }
    cwg[e] = f2b(v);
}

// ---------------------------------------------------------------------------
// Kernel 1: STFT magnitude + sensor fusion via MFMA.
// One block per batch b, 512 threads (8 waves). A = raw x samples bf16
// (window folded into basis), M rows = t*8+s (24 tiles, 264 valid),
// N = 160 basis rows, K = 128.
// Frag layouts (verified, learn_hip m89/m91/m120):
//   A: lane holds A[m=lane&15][k=quad*8+j]   B: B[k=quad*8+j][n=lane&15]
//   C/D: col=lane&15, row=quad*4+reg
// Epilogue: rows q*4+reg within a tile = 4 sensors of one frame-half ->
// in-lane weighted mag sum, one LDS atomicAdd per lane per re-tile.
// ---------------------------------------------------------------------------
__global__ __launch_bounds__(512)
void sf_stft_fuse(const float* __restrict__ x,
                  const float* __restrict__ wsoft,
                  const unsigned short* __restrict__ cwg,
                  float* __restrict__ h0) {
    __shared__ __align__(16) unsigned short xbp[NSENS * XROW];   // 35.1 KB
    __shared__ __align__(16) unsigned short cw[NB * CWROW];      // 42.5 KB
    __shared__ float fuse[NFRAMES * NFREQ];                      // 8.4 KB
    __shared__ float wsens[NSENS];

    const int b   = blockIdx.x;
    const int tid = threadIdx.x;

    // ---- Phase 1: stage x[b] (bf16, sensor-major, zero-padded), basis, init
    const float4* xb4 = (const float4*)(x + (size_t)b * (LEN * NSENS));
    for (int e = tid; e < LEN * NSENS / 4; e += 512) {     // 4096 float4s
        float4 v = xb4[e];
        int l  = e >> 1;            // sample index 0..2047
        int sh = (e & 1) * 4;       // sensor base 0 or 4
        xbp[(sh + 0) * XROW + 64 + l] = f2b(v.x);
        xbp[(sh + 1) * XROW + 64 + l] = f2b(v.y);
        xbp[(sh + 2) * XROW + 64 + l] = f2b(v.z);
        xbp[(sh + 3) * XROW + 64 + l] = f2b(v.w);
    }
    for (int e = tid; e < NSENS * 64; e += 512)            // left pad
        xbp[(e >> 6) * XROW + (e & 63)] = 0;
    for (int e = tid; e < NSENS * 136; e += 512) {         // right pad + row tail
        int s = e / 136;
        xbp[s * XROW + 2112 + (e - s * 136)] = 0;
    }
    for (int e = tid; e < NB * CWROW / 8; e += 512)        // basis: 16B copies
        ((float4*)cw)[e] = ((const float4*)cwg)[e];
    for (int e = tid; e < NFRAMES * NFREQ; e += 512)
        fuse[e] = 0.f;
    if (tid < NSENS) wsens[tid] = wsoft[tid];
    __syncthreads();

    // ---- Phase 2: MFMA + fused-magnitude epilogue
    const int lane = tid & 63;
    const int wv   = tid >> 6;          // wave 0..7
    const int col  = lane & 15;
    const int q    = lane >> 4;

    float wqa[4];
    *(float4*)wqa = *(const float4*)&wsens[(q & 1) * 4];   // sensors for this lane's 4 acc regs

    // A-fragment bases for this wave's 3 M-tiles
    const unsigned short* abase[MT_PER_WAVE];
    #pragma unroll
    for (int mb = 0; mb < MT_PER_WAVE; ++mb) {
        int mi = wv * MT_PER_WAVE + mb;          // 0..23
        int m  = mi * 16 + col;                  // A row
        int ta = m >> 3; if (ta > NFRAMES) ta = NFRAMES;   // clamp into zero pad
        int sa = m & 7;
        abase[mb] = &xbp[sa * XROW + ta * HOP + q * 8];
    }

    float4v acc[MT_PER_WAVE][NTILES];
    #pragma unroll
    for (int mb = 0; mb < MT_PER_WAVE; ++mb)
        #pragma unroll
        for (int ni = 0; ni < NTILES; ++ni)
            acc[mb][ni] = (float4v){0.f, 0.f, 0.f, 0.f};

    #pragma unroll
    for (int ks = 0; ks < 4; ++ks) {
        short8 af[MT_PER_WAVE];
        #pragma unroll
        for (int mb = 0; mb < MT_PER_WAVE; ++mb)
            af[mb] = *(const short8*)(abase[mb] + ks * 32);
        #pragma unroll
        for (int ni = 0; ni < NTILES; ++ni) {
            short8 bf = *(const short8*)&cw[(ni * 16 + col) * CWROW + ks * 32 + q * 8];
            #pragma unroll
            for (int mb = 0; mb < MT_PER_WAVE; ++mb)
                acc[mb][ni] = __builtin_amdgcn_mfma_f32_16x16x32_bf16(af[mb], bf, acc[mb][ni], 0, 0, 0);
        }
    }

    #pragma unroll
    for (int mb = 0; mb < MT_PER_WAVE; ++mb) {
        int mi = wv * MT_PER_WAVE + mb;
        int t  = mi * 2 + (q >> 1);              // frame index for this lane's acc rows
        if (t < NFRAMES) {
            #pragma unroll
            for (int ni = 0; ni < 5; ++ni) {     // re tile ni, im tile ni+5
                int f = ni * 16 + col;
                if (f < NFREQ) {
                    float ps = 0.f;
                    #pragma unroll
                    for (int r = 0; r < 4; ++r) {
                        float re = acc[mb][ni][r];
                        float im = acc[mb][ni + 5][r];
                        ps += wqa[r] * sqrtf(re * re + im * im);
                    }
                    atomicAdd(&fuse[t * NFREQ + f], ps);
                }
            }
        }
    }
    __syncthreads();

    // ---- Phase 3: write h0[b][f*33+t] (coalesced)
    for (int e = tid; e < FEAT; e += 512) {
        int f = e / NFRAMES;
        int t = e - f * NFRAMES;
        h0[(size_t)b * FEAT + e] = fuse[t * NFREQ + f];
    }
}

// ---------------------------------------------------------------------------
// Kernel 2: generic fp32 NT-GEMM with fused bias (+ optional ReLU).
// (unchanged from round 1 — verified)
// ---------------------------------------------------------------------------
template <int RELU>
__global__ __launch_bounds__(256)
void sf_gemm_nt(const float* __restrict__ A, const float* __restrict__ W,
                const float* __restrict__ bias, float* __restrict__ C,
                int M, int N, int K) {
    const int BM = 64, BK = 16, STR = 68;
    __shared__ __align__(16) float As[BK * STR];
    __shared__ __align__(16) float Ws[BK * STR];

    const int tid = threadIdx.x;
    const int tx  = tid & 15;
    const int ty  = tid >> 4;
    const int m0  = blockIdx.y * BM;
    const int n0  = blockIdx.x * BM;

    float acc[4][4] = {};

    for (int k0 = 0; k0 < K; k0 += BK) {
        for (int e = tid; e < BM * BK; e += 256) {
            int r = e >> 4;
            int k = e & 15;
            bool kok = (k0 + k) < K;
            float va = kok ? A[(long)(m0 + r) * K + k0 + k] : 0.f;
            As[k * STR + r] = va;
            float vw = (kok && (n0 + r) < N) ? W[(long)(n0 + r) * K + k0 + k] : 0.f;
            Ws[k * STR + r] = vw;
        }
        __syncthreads();
        #pragma unroll
        for (int kk = 0; kk < BK; ++kk) {
            const float4 a4 = *(const float4*)&As[kk * STR + ty * 4];
            const float4 w4 = *(const float4*)&Ws[kk * STR + tx * 4];
            const float a[4] = {a4.x, a4.y, a4.z, a4.w};
            const float w[4] = {w4.x, w4.y, w4.z, w4.w};
            #pragma unroll
            for (int i = 0; i < 4; ++i)
                #pragma unroll
                for (int j = 0; j < 4; ++j)
                    acc[i][j] = fmaf(a[i], w[j], acc[i][j]);
        }
        __syncthreads();
    }

    #pragma unroll
    for (int i = 0; i < 4; ++i) {
        int m = m0 + ty * 4 + i;
        #pragma unroll
        for (int j = 0; j < 4; ++j) {
            int n = n0 + tx * 4 + j;
            if (n < N) {
                float v = acc[i][j] + bias[n];
                if (RELU) v = fmaxf(v, 0.f);
                C[(long)m * N + n] = v;
            }
        }
    }
}

// ---------------------------------------------------------------------------
extern "C" void kernel_launch(void* const* d_in, const int* in_sizes, int n_in,
                              void* d_out, int out_size, void* d_ws, size_t ws_size,
                              hipStream_t stream) {
    const float* x  = (const float*)d_in[0];
    const float* sw = (const float*)d_in[1];
    const float* W1 = (const float*)d_in[2];
    const float* b1 = (const float*)d_in[3];
    const float* W2 = (const float*)d_in[4];
    const float* b2 = (const float*)d_in[5];
    const float* W3 = (const float*)d_in[6];
    const float* b3 = (const float*)d_in[7];
    const float* W4 = (const float*)d_in[8];
    const float* b4 = (const float*)d_in[9];
    float* out = (float*)d_out;

    float* ws    = (float*)d_ws;
    float* wsoft = ws;                                   // 16 floats
    unsigned short* cwg = (unsigned short*)(ws + 16);    // 160*136 bf16 = 43520 B
    float* h0    = ws + 16 + (NB * CWROW / 2);           // 2048 x 2145 (16B-aligned)
    float* h1    = h0 + (size_t)BATCH * FEAT;            // 2048 x 1024
    float* h2    = h1 + (size_t)BATCH * H1;              // 2048 x 512
    float* h3    = h2 + (size_t)BATCH * H2;              // 2048 x 256

    sf_softmax8<<<1, 64, 0, stream>>>(sw, wsoft);
    sf_basis<<<(NB * CWROW + 255) / 256, 256, 0, stream>>>(cwg);
    sf_stft_fuse<<<BATCH, 512, 0, stream>>>(x, wsoft, cwg, h0);

    sf_gemm_nt<1><<<dim3(H1 / 64,  BATCH / 64), 256, 0, stream>>>(h0, W1, b1, h1, BATCH, H1, FEAT);
    sf_gemm_nt<1><<<dim3(H2 / 64,  BATCH / 64), 256, 0, stream>>>(h1, W2, b2, h2, BATCH, H2, H1);
    sf_gemm_nt<1><<<dim3(H3 / 64,  BATCH / 64), 256, 0, stream>>>(h2, W3, b3, h3, BATCH, H3, H2);
    sf_gemm_nt<0><<<dim3(1,        BATCH / 64), 256, 0, stream>>>(h3, W4, b4, out, BATCH, NOUT, H3);
}

// Round 3
// 402.837 us; speedup vs baseline: 4.8570x; 2.5001x over previous
//
#include <hip/hip_runtime.h>
#include <hip/hip_bf16.h>
#include <math.h>

#define NPERSEG 128
#define HOP     64
#define NFRAMES 33
#define NFREQ   65
#define BATCH   2048
#define LEN     2048
#define NSENS   8
#define FEAT    (NFREQ * NFRAMES)   // 2145
#define FEATP   2176                // FEAT padded to multiple of 32
#define H1      1024
#define H2      512
#define H3      256
#define NOUT    10

// STFT-as-GEMM geometry
#define XROW    2248
#define CWROW   136
#define NB      160
#define NTILES  10
#define MT_PER_WAVE 3

typedef __attribute__((ext_vector_type(8))) short short8;     // 8 bf16 = 4 VGPRs
typedef __attribute__((ext_vector_type(4))) float float4v;    // MFMA C/D
typedef unsigned short ushort;

__device__ __forceinline__ ushort f2b(float v) {
    __hip_bfloat16 h = __float2bfloat16(v);
    return *reinterpret_cast<ushort*>(&h);
}
__device__ __forceinline__ float b2f(ushort u) {
    union { unsigned int i; float f; } c; c.i = ((unsigned int)u) << 16; return c.f;
}
__device__ __forceinline__ void gl_lds16(const void* g, void* l) {
    __builtin_amdgcn_global_load_lds(
        (const __attribute__((address_space(1))) unsigned int*)g,
        (__attribute__((address_space(3))) unsigned int*)l, 16, 0, 0);
}

// ---------------------------------------------------------------------------
// Kernel 0: softmax over the 8 sensor weights.
// ---------------------------------------------------------------------------
__global__ void sf_softmax8(const float* __restrict__ w, float* __restrict__ out) {
    if (threadIdx.x == 0) {
        float m = w[0];
        for (int s = 1; s < NSENS; ++s) m = fmaxf(m, w[s]);
        float e[NSENS];
        float sum = 0.f;
        for (int s = 0; s < NSENS; ++s) { e[s] = expf(w[s] - m); sum += e[s]; }
        float inv = 1.0f / sum;
        for (int s = 0; s < NSENS; ++s) out[s] = e[s] * inv;
    }
}

// ---------------------------------------------------------------------------
// Kernel 0b: windowed DFT basis in bf16 (window + 1/64 norm folded in).
// ---------------------------------------------------------------------------
__global__ void sf_basis(ushort* __restrict__ cwg) {
    int e = blockIdx.x * 256 + threadIdx.x;
    if (e >= NB * CWROW) return;
    int n = e / CWROW, k = e - n * CWROW;
    const float TWO_PI = 6.28318530717958647692f;
    float v = 0.f;
    if (k < NPERSEG) {
        float win = 0.5f - 0.5f * cosf(TWO_PI * (float)k / (float)NPERSEG);
        if (n < NFREQ) {
            int r = (n * k) & (NPERSEG - 1);
            v = win * cosf(TWO_PI * (float)r / (float)NPERSEG) * (1.0f / 64.0f);
        } else if (n >= 80 && n < 80 + NFREQ) {
            int r = ((n - 80) * k) & (NPERSEG - 1);
            v = win * sinf(TWO_PI * (float)r / (float)NPERSEG) * (1.0f / 64.0f);
        }
    }
    cwg[e] = f2b(v);
}

// ---------------------------------------------------------------------------
// Kernel 0c: fp32 -> bf16 weight convert with K padding (zeros in pad).
// ---------------------------------------------------------------------------
__global__ void sf_cvt_w(const float* __restrict__ src, ushort* __restrict__ dst,
                         int N, int K, int Kp) {
    int e = blockIdx.x * 256 + threadIdx.x;
    if (e >= N * Kp) return;
    int n = e / Kp, k = e - n * Kp;
    dst[e] = f2b(k < K ? src[(long)n * K + k] : 0.f);
}

// ---------------------------------------------------------------------------
// Kernel 1: STFT magnitude + sensor fusion via MFMA (verified round 2).
// Now emits h0 as bf16 with row stride FEATP (pad cols zeroed).
// ---------------------------------------------------------------------------
__global__ __launch_bounds__(512)
void sf_stft_fuse(const float* __restrict__ x,
                  const float* __restrict__ wsoft,
                  const ushort* __restrict__ cwg,
                  ushort* __restrict__ h0) {
    __shared__ __align__(16) ushort xbp[NSENS * XROW];
    __shared__ __align__(16) ushort cw[NB * CWROW];
    __shared__ float fuse[NFRAMES * NFREQ];
    __shared__ float wsens[NSENS];

    const int b   = blockIdx.x;
    const int tid = threadIdx.x;

    const float4* xb4 = (const float4*)(x + (size_t)b * (LEN * NSENS));
    for (int e = tid; e < LEN * NSENS / 4; e += 512) {
        float4 v = xb4[e];
        int l  = e >> 1;
        int sh = (e & 1) * 4;
        xbp[(sh + 0) * XROW + 64 + l] = f2b(v.x);
        xbp[(sh + 1) * XROW + 64 + l] = f2b(v.y);
        xbp[(sh + 2) * XROW + 64 + l] = f2b(v.z);
        xbp[(sh + 3) * XROW + 64 + l] = f2b(v.w);
    }
    for (int e = tid; e < NSENS * 64; e += 512)
        xbp[(e >> 6) * XROW + (e & 63)] = 0;
    for (int e = tid; e < NSENS * 136; e += 512) {
        int s = e / 136;
        xbp[s * XROW + 2112 + (e - s * 136)] = 0;
    }
    for (int e = tid; e < NB * CWROW / 8; e += 512)
        ((float4*)cw)[e] = ((const float4*)cwg)[e];
    for (int e = tid; e < NFRAMES * NFREQ; e += 512)
        fuse[e] = 0.f;
    if (tid < NSENS) wsens[tid] = wsoft[tid];
    __syncthreads();

    const int lane = tid & 63;
    const int wv   = tid >> 6;
    const int col  = lane & 15;
    const int q    = lane >> 4;

    float wqa[4];
    *(float4*)wqa = *(const float4*)&wsens[(q & 1) * 4];

    const ushort* abase[MT_PER_WAVE];
    #pragma unroll
    for (int mb = 0; mb < MT_PER_WAVE; ++mb) {
        int mi = wv * MT_PER_WAVE + mb;
        int m  = mi * 16 + col;
        int ta = m >> 3; if (ta > NFRAMES) ta = NFRAMES;
        int sa = m & 7;
        abase[mb] = &xbp[sa * XROW + ta * HOP + q * 8];
    }

    float4v acc[MT_PER_WAVE][NTILES];
    #pragma unroll
    for (int mb = 0; mb < MT_PER_WAVE; ++mb)
        #pragma unroll
        for (int ni = 0; ni < NTILES; ++ni)
            acc[mb][ni] = (float4v){0.f, 0.f, 0.f, 0.f};

    #pragma unroll
    for (int ks = 0; ks < 4; ++ks) {
        short8 af[MT_PER_WAVE];
        #pragma unroll
        for (int mb = 0; mb < MT_PER_WAVE; ++mb)
            af[mb] = *(const short8*)(abase[mb] + ks * 32);
        #pragma unroll
        for (int ni = 0; ni < NTILES; ++ni) {
            short8 bf = *(const short8*)&cw[(ni * 16 + col) * CWROW + ks * 32 + q * 8];
            #pragma unroll
            for (int mb = 0; mb < MT_PER_WAVE; ++mb)
                acc[mb][ni] = __builtin_amdgcn_mfma_f32_16x16x32_bf16(af[mb], bf, acc[mb][ni], 0, 0, 0);
        }
    }

    #pragma unroll
    for (int mb = 0; mb < MT_PER_WAVE; ++mb) {
        int mi = wv * MT_PER_WAVE + mb;
        int t  = mi * 2 + (q >> 1);
        if (t < NFRAMES) {
            #pragma unroll
            for (int ni = 0; ni < 5; ++ni) {
                int f = ni * 16 + col;
                if (f < NFREQ) {
                    float ps = 0.f;
                    #pragma unroll
                    for (int r = 0; r < 4; ++r) {
                        float re = acc[mb][ni][r];
                        float im = acc[mb][ni + 5][r];
                        ps += wqa[r] * sqrtf(re * re + im * im);
                    }
                    atomicAdd(&fuse[t * NFREQ + f], ps);
                }
            }
        }
    }
    __syncthreads();

    for (int e = tid; e < FEATP; e += 512) {
        float v = 0.f;
        if (e < FEAT) {
            int f = e / NFRAMES;
            int t = e - f * NFRAMES;
            v = fuse[t * NFREQ + f];
        }
        h0[(size_t)b * FEATP + e] = f2b(v);
    }
}

// ---------------------------------------------------------------------------
// Kernel 2: bf16 MFMA NT-GEMM, m97 structure. C[m,n]=act(A[m,:]·W[n,:]+bias).
// 128x128 tile, BK=32, 256 thr (4 waves, 2x2), wave = 64x64 = 4x4 MFMA tiles.
// Staging via global_load_lds width 16; LDS rows 64B with XOR-chunk swizzle
// (chunk ^= (row>>1)&3) so frag ds_read_b128 is 2-way-per-bank (free, m136).
// M,N multiples of 128; K multiple of 32. Output bf16.
// ---------------------------------------------------------------------------
template <int RELU>
__global__ __launch_bounds__(256)
void sf_gemm_mfma(const ushort* __restrict__ A, const ushort* __restrict__ W,
                  const float* __restrict__ bias, ushort* __restrict__ C,
                  int M, int N, int K) {
    __shared__ __align__(16) ushort As[128 * 32];   // 8 KB
    __shared__ __align__(16) ushort Bs[128 * 32];   // 8 KB

    const int tid  = threadIdx.x;
    const int lane = tid & 63;
    const int wv   = tid >> 6;          // 0..3
    const int wrow = wv >> 1;           // 0..1  (m half)
    const int wcol = wv & 1;            // 0..1  (n half)
    const int col  = lane & 15;
    const int q    = lane >> 4;

    const int m0 = blockIdx.y * 128;
    const int n0 = blockIdx.x * 128;

    // staging geometry: lane l covers (row = chunk*16 + l>>2, kchunk = (l&3)^((l>>3)&3))
    const int srow = lane >> 2;
    const int skch = (lane & 3) ^ ((lane >> 3) & 3);

    float4v acc[4][4];
    #pragma unroll
    for (int mi = 0; mi < 4; ++mi)
        #pragma unroll
        for (int ni = 0; ni < 4; ++ni)
            acc[mi][ni] = (float4v){0.f, 0.f, 0.f, 0.f};

    // frag read offsets (XOR-swizzled): row r holds data-chunk q at slot q^((r>>1)&3)
    const int fsw = ((col >> 1) & 3);
    int aoff[4], boff[4];
    #pragma unroll
    for (int i = 0; i < 4; ++i) {
        aoff[i] = (wrow * 64 + i * 16 + col) * 32 + ((q ^ fsw) * 8);
        boff[i] = (wcol * 64 + i * 16 + col) * 32 + ((q ^ fsw) * 8);
    }

    for (int k0 = 0; k0 < K; k0 += 32) {
        #pragma unroll
        for (int i = 0; i < 2; ++i) {
            int c = wv * 2 + i;                         // chunk 0..7 (16 rows each)
            int r = c * 16 + srow;
            gl_lds16(A + (size_t)(m0 + r) * K + k0 + skch * 8, &As[c * 16 * 32]);
            gl_lds16(W + (size_t)(n0 + r) * K + k0 + skch * 8, &Bs[c * 16 * 32]);
        }
        __syncthreads();

        short8 af[4], bf[4];
        #pragma unroll
        for (int i = 0; i < 4; ++i) {
            af[i] = *(const short8*)&As[aoff[i]];
            bf[i] = *(const short8*)&Bs[boff[i]];
        }
        #pragma unroll
        for (int mi = 0; mi < 4; ++mi)
            #pragma unroll
            for (int ni = 0; ni < 4; ++ni)
                acc[mi][ni] = __builtin_amdgcn_mfma_f32_16x16x32_bf16(af[mi], bf[ni], acc[mi][ni], 0, 0, 0);
        __syncthreads();
    }

    #pragma unroll
    for (int ni = 0; ni < 4; ++ni) {
        int n = n0 + wcol * 64 + ni * 16 + col;
        float bn = bias[n];
        #pragma unroll
        for (int mi = 0; mi < 4; ++mi) {
            int mbase = m0 + wrow * 64 + mi * 16 + q * 4;
            #pragma unroll
            for (int r = 0; r < 4; ++r) {
                float v = acc[mi][ni][r] + bn;
                if (RELU) v = fmaxf(v, 0.f);
                C[(size_t)(mbase + r) * N + n] = f2b(v);
            }
        }
    }
}

// ---------------------------------------------------------------------------
// Kernel 3: final tiny layer, fp32 out. out[m,n] = h3[m,:]·W4[n,:] + b4[n].
// ---------------------------------------------------------------------------
__global__ __launch_bounds__(256)
void sf_final(const ushort* __restrict__ h3, const float* __restrict__ W4,
              const float* __restrict__ b4, float* __restrict__ out) {
    int o = blockIdx.x * 256 + threadIdx.x;
    if (o >= BATCH * NOUT) return;
    int m = o / NOUT, n = o - m * NOUT;
    const ushort* a = h3 + (size_t)m * H3;
    const float* w = W4 + (size_t)n * H3;
    float s = 0.f;
    #pragma unroll 8
    for (int k = 0; k < H3; ++k) s = fmaf(b2f(a[k]), w[k], s);
    out[o] = s + b4[n];
}

// ---------------------------------------------------------------------------
extern "C" void kernel_launch(void* const* d_in, const int* in_sizes, int n_in,
                              void* d_out, int out_size, void* d_ws, size_t ws_size,
                              hipStream_t stream) {
    const float* x  = (const float*)d_in[0];
    const float* sw = (const float*)d_in[1];
    const float* W1 = (const float*)d_in[2];
    const float* b1 = (const float*)d_in[3];
    const float* W2 = (const float*)d_in[4];
    const float* b2 = (const float*)d_in[5];
    const float* W3 = (const float*)d_in[6];
    const float* b3 = (const float*)d_in[7];
    const float* W4 = (const float*)d_in[8];
    const float* b4 = (const float*)d_in[9];
    float* out = (float*)d_out;

    char* cur = (char*)d_ws;
    float* wsoft = (float*)cur;                 cur += 64;
    ushort* cwg  = (ushort*)cur;                cur += NB * CWROW * 2;            // 43.5 KB
    ushort* h0   = (ushort*)cur;                cur += (size_t)BATCH * FEATP * 2; // 8.9 MB
    ushort* W1b  = (ushort*)cur;                cur += (size_t)H1 * FEATP * 2;    // 4.5 MB
    ushort* W2b  = (ushort*)cur;                cur += (size_t)H2 * H1 * 2;       // 1.0 MB
    ushort* W3b  = (ushort*)cur;                cur += (size_t)H3 * H2 * 2;       // 0.3 MB
    ushort* h1   = (ushort*)cur;                cur += (size_t)BATCH * H1 * 2;    // 4.2 MB
    ushort* h2   = (ushort*)cur;                cur += (size_t)BATCH * H2 * 2;    // 2.1 MB
    ushort* h3   = (ushort*)cur;                cur += (size_t)BATCH * H3 * 2;    // 1.0 MB

    sf_softmax8<<<1, 64, 0, stream>>>(sw, wsoft);
    sf_basis<<<(NB * CWROW + 255) / 256, 256, 0, stream>>>(cwg);
    sf_cvt_w<<<(H1 * FEATP + 255) / 256, 256, 0, stream>>>(W1, W1b, H1, FEAT, FEATP);
    sf_cvt_w<<<(H2 * H1 + 255) / 256, 256, 0, stream>>>(W2, W2b, H2, H1, H1);
    sf_cvt_w<<<(H3 * H2 + 255) / 256, 256, 0, stream>>>(W3, W3b, H3, H2, H2);

    sf_stft_fuse<<<BATCH, 512, 0, stream>>>(x, wsoft, cwg, h0);

    sf_gemm_mfma<1><<<dim3(H1 / 128, BATCH / 128), 256, 0, stream>>>(h0, W1b, b1, h1, BATCH, H1, FEATP);
    sf_gemm_mfma<1><<<dim3(H2 / 128, BATCH / 128), 256, 0, stream>>>(h1, W2b, b2, h2, BATCH, H2, H1);
    sf_gemm_mfma<1><<<dim3(H3 / 128, BATCH / 128), 256, 0, stream>>>(h2, W3b, b3, h3, BATCH, H3, H2);
    sf_final<<<(BATCH * NOUT + 255) / 256, 256, 0, stream>>>(h3, W4, b4, out);
}